// Round 6
// baseline (363.535 us; speedup 1.0000x reference)
//
#include <hip/hip_runtime.h>
#include <math.h>

constexpr int IN   = 512;
constexpr int HID  = 128;
constexpr int OUTD = 64;
constexpr int KC   = 20;
#define LRELU_SLOPE 0.2f

typedef _Float16 half8 __attribute__((ext_vector_type(8)));
typedef _Float16 half2v __attribute__((ext_vector_type(2)));
typedef float f32x16 __attribute__((ext_vector_type(16)));

__device__ __forceinline__ float warp_sum(float v) {
#pragma unroll
  for (int o = 32; o > 0; o >>= 1) v += __shfl_xor(v, o, 64);
  return v;
}

// ---------------- prep: transpose+convert weights to f16 [col][K]; zero counts ----------------
__global__ __launch_bounds__(256) void k_prep(const float* __restrict__ Wg,
                                              const float* __restrict__ We,
                                              const float* __restrict__ Wd,
                                              _Float16* Bg, _Float16* Be, _Float16* Bd,
                                              int* counts, int N) {
  int i = blockIdx.x * 256 + threadIdx.x;
  if (i < N) counts[i] = 0;
  if (i < HID * IN) {                 // Bg[c][k] = Wg[k][c], c<128,k<512
    int c = i >> 9, k = i & 511;
    Bg[i] = (_Float16)Wg[(size_t)k * HID + c];
    return;
  }
  i -= HID * IN;
  if (i < OUTD * HID) {               // Be[c][k] = We[k][c], c<64,k<128
    int c = i >> 7, k = i & 127;
    Be[i] = (_Float16)We[(size_t)k * OUTD + c];
    return;
  }
  i -= OUTD * HID;
  if (i < IN * OUTD) {                // Bd[c][k] = Wd[k][c], c<512,k<64
    int c = i >> 6, k = i & 63;
    Bd[i] = (_Float16)Wd[(size_t)k * IN + c];
  }
}

// ---------------- GEMM1 (+fused el/er): h(f16) = x @ W_gat  (M x 512)(512 x 128) ----------------
// block 128x128, BK=64, 4 waves 2x2, wave tile 64x64; epilogue computes el/er per row
__global__ __launch_bounds__(256) void k_gemm1e(const float* __restrict__ A,
                                                const _Float16* __restrict__ Bt,
                                                const float* __restrict__ al,
                                                const float* __restrict__ ar,
                                                _Float16* __restrict__ H,
                                                float* __restrict__ el,
                                                float* __restrict__ er, int M) {
  __shared__ _Float16 As[128 * 72];
  __shared__ _Float16 Bs[128 * 72];
  const int tid = threadIdx.x;
  const int lane = tid & 63, wid = tid >> 6;
  const int wrow = (wid >> 1) * 64, wcol = (wid & 1) * 64;
  const int row0 = blockIdx.x * 128;
  const int l31 = lane & 31, lhi = lane >> 5;

  f32x16 acc[2][2] = {};

  for (int k0 = 0; k0 < IN; k0 += 64) {
#pragma unroll
    for (int c = 0; c < 4; ++c) {       // A: 128 rows x 8 k-octets
      int idx = tid + c * 256;
      int r = idx >> 3, ko = idx & 7;
      int gr = row0 + r;
      float4 v0 = make_float4(0.f, 0.f, 0.f, 0.f), v1 = v0;
      if (gr < M) {
        const float* p = A + (size_t)gr * IN + k0 + ko * 8;
        v0 = *(const float4*)p;
        v1 = *(const float4*)(p + 4);
      }
      half8 hv;
      hv[0] = (_Float16)v0.x; hv[1] = (_Float16)v0.y; hv[2] = (_Float16)v0.z; hv[3] = (_Float16)v0.w;
      hv[4] = (_Float16)v1.x; hv[5] = (_Float16)v1.y; hv[6] = (_Float16)v1.z; hv[7] = (_Float16)v1.w;
      *(half8*)(&As[r * 72 + ko * 8]) = hv;
    }
#pragma unroll
    for (int c = 0; c < 4; ++c) {       // B: 128 cols x 8 k-octets ([col][K] f16)
      int idx = tid + c * 256;
      int col = idx >> 3, ko = idx & 7;
      *(half8*)(&Bs[col * 72 + ko * 8]) = *(const half8*)(Bt + (size_t)col * IN + k0 + ko * 8);
    }
    __syncthreads();
#pragma unroll
    for (int ks = 0; ks < 4; ++ks) {
      half8 a0 = *(half8*)(&As[(wrow + l31) * 72      + ks * 16 + lhi * 8]);
      half8 a1 = *(half8*)(&As[(wrow + 32 + l31) * 72 + ks * 16 + lhi * 8]);
      half8 b0 = *(half8*)(&Bs[(wcol + l31) * 72      + ks * 16 + lhi * 8]);
      half8 b1 = *(half8*)(&Bs[(wcol + 32 + l31) * 72 + ks * 16 + lhi * 8]);
      acc[0][0] = __builtin_amdgcn_mfma_f32_32x32x16_f16(a0, b0, acc[0][0], 0, 0, 0);
      acc[0][1] = __builtin_amdgcn_mfma_f32_32x32x16_f16(a0, b1, acc[0][1], 0, 0, 0);
      acc[1][0] = __builtin_amdgcn_mfma_f32_32x32x16_f16(a1, b0, acc[1][0], 0, 0, 0);
      acc[1][1] = __builtin_amdgcn_mfma_f32_32x32x16_f16(a1, b1, acc[1][1], 0, 0, 0);
    }
    __syncthreads();
  }
  // h write
#pragma unroll
  for (int mr = 0; mr < 2; ++mr)
#pragma unroll
    for (int r = 0; r < 16; ++r) {
      int row = row0 + wrow + mr * 32 + (r & 3) + 8 * (r >> 2) + 4 * lhi;
      if (row < M) {
#pragma unroll
        for (int nr = 0; nr < 2; ++nr)
          H[(size_t)row * HID + wcol + nr * 32 + l31] = (_Float16)acc[mr][nr][r];
      }
    }
  // fused el/er: per-wave partial dots, reduce over l31, combine column halves in LDS
  float* elp = (float*)As;          // [128][2]
  float* erp = elp + 256;           // [128][2]
  float alw0 = al[wcol + l31], alw1 = al[wcol + 32 + l31];
  float arw0 = ar[wcol + l31], arw1 = ar[wcol + 32 + l31];
#pragma unroll
  for (int mr = 0; mr < 2; ++mr)
#pragma unroll
    for (int r = 0; r < 16; ++r) {
      float pe  = acc[mr][0][r] * alw0 + acc[mr][1][r] * alw1;
      float pr_ = acc[mr][0][r] * arw0 + acc[mr][1][r] * arw1;
#pragma unroll
      for (int o = 1; o <= 16; o <<= 1) {
        pe  += __shfl_xor(pe, o, 64);
        pr_ += __shfl_xor(pr_, o, 64);
      }
      if (l31 == 0) {
        int lr = wrow + mr * 32 + (r & 3) + 8 * (r >> 2) + 4 * lhi;
        elp[lr * 2 + (wid & 1)] = pe;
        erp[lr * 2 + (wid & 1)] = pr_;
      }
    }
  __syncthreads();
  if (tid < 128) {
    int row = row0 + tid;
    if (row < M) {
      el[row] = elp[tid * 2] + elp[tid * 2 + 1];
      er[row] = erp[tid * 2] + erp[tid * 2 + 1];
    }
  }
}

// ---------------- CSR build ----------------
__global__ void k_hist(const int* __restrict__ dst, int* counts, int E) {
  int i = (blockIdx.x * blockDim.x + threadIdx.x) * 4;
  if (i + 4 <= E) {
    int4 d = *(const int4*)(dst + i);
    atomicAdd(&counts[d.x], 1); atomicAdd(&counts[d.y], 1);
    atomicAdd(&counts[d.z], 1); atomicAdd(&counts[d.w], 1);
  } else {
    for (; i < E; ++i) atomicAdd(&counts[dst[i]], 1);
  }
}

__global__ __launch_bounds__(256) void k_scan1(const int* __restrict__ counts, int* bsum, int N) {
  __shared__ int s[256];
  int b = blockIdx.x, t = threadIdx.x;
  int i0 = b * 512 + t * 2;
  int v = 0;
  if (i0 < N) v += counts[i0];
  if (i0 + 1 < N) v += counts[i0 + 1];
  s[t] = v;
  __syncthreads();
  for (int off = 128; off > 0; off >>= 1) {
    if (t < off) s[t] += s[t + off];
    __syncthreads();
  }
  if (t == 0) bsum[b] = s[0];
}

// scan2 merged in: each block redundantly prefix-sums bsum (nblk<=256)
__global__ __launch_bounds__(256) void k_scan3m(const int* __restrict__ counts,
                                                const int* __restrict__ bsum,
                                                int* rowptr, int* cursor, int N, int nblk) {
  __shared__ int sb[256];
  __shared__ int s[256];
  int b = blockIdx.x, t = threadIdx.x;
  int v = (t < nblk) ? bsum[t] : 0;
  sb[t] = v;
  __syncthreads();
#pragma unroll
  for (int off = 1; off < 256; off <<= 1) {
    int u = 0;
    if (t >= off) u = sb[t - off];
    __syncthreads();
    sb[t] += u;
    __syncthreads();
  }
  int boffb = (b == 0) ? 0 : sb[b - 1];

  int i0 = b * 512 + t * 2;
  int c0 = (i0 < N) ? counts[i0] : 0;
  int c1 = (i0 + 1 < N) ? counts[i0 + 1] : 0;
  int tsum = c0 + c1;
  s[t] = tsum;
  __syncthreads();
#pragma unroll
  for (int off = 1; off < 256; off <<= 1) {
    int u = 0;
    if (t >= off) u = s[t - off];
    __syncthreads();
    s[t] += u;
    __syncthreads();
  }
  int base = boffb + s[t] - tsum;
  if (i0 < N)     { rowptr[i0] = base;          cursor[i0] = base; }
  if (i0 + 1 < N) { rowptr[i0 + 1] = base + c0; cursor[i0 + 1] = base + c0; }
}

__global__ void k_fill(const int* __restrict__ src, const int* __restrict__ dst,
                       int* cursor, int* colsrc, int E) {
  int i = (blockIdx.x * blockDim.x + threadIdx.x) * 4;
  if (i + 4 <= E) {
    int4 sv = *(const int4*)(src + i);
    int4 dv = *(const int4*)(dst + i);
    colsrc[atomicAdd(&cursor[dv.x], 1)] = sv.x;
    colsrc[atomicAdd(&cursor[dv.y], 1)] = sv.y;
    colsrc[atomicAdd(&cursor[dv.z], 1)] = sv.z;
    colsrc[atomicAdd(&cursor[dv.w], 1)] = sv.w;
  } else {
    for (; i < E; ++i) {
      int d = dst[i];
      colsrc[atomicAdd(&cursor[d], 1)] = src[i];
    }
  }
}

// ---------------- edge softmax + aggregation + elu -> eh(f16) ----------------
__global__ __launch_bounds__(256) void k_agg(const _Float16* __restrict__ h,
                                             const float* __restrict__ el,
                                             const float* __restrict__ er,
                                             const int* __restrict__ rowptr,
                                             const int* __restrict__ counts,
                                             const int* __restrict__ colsrc,
                                             const float* __restrict__ bias,
                                             _Float16* __restrict__ eh, int N) {
  int g = blockIdx.x * blockDim.x + threadIdx.x;
  int v = g >> 6, lane = g & 63;
  if (v >= N) return;
  int start = rowptr[v], deg = counts[v];
  float erv = er[v];

  float a0 = 0.f, a1 = 0.f, den = 0.f;
  for (int base = 0; base < deg; base += 64) {
    int cnt = deg - base; if (cnt > 64) cnt = 64;
    int u_l = 0; float w_l = 0.f;
    if (lane < cnt) {
      u_l = colsrc[start + base + lane];
      float e = el[u_l] + erv;
      e = (e > 0.f) ? e : LRELU_SLOPE * e;
      w_l = __expf(e);                  // softmax shift-invariant; e bounded
    }
    den += warp_sum(w_l);
    int cntR = (cnt + 3) & ~3;
    for (int j = 0; j < cntR; j += 4) {
      int   u0 = __shfl(u_l, j, 64),     u1 = __shfl(u_l, j + 1, 64);
      int   u2 = __shfl(u_l, j + 2, 64), u3 = __shfl(u_l, j + 3, 64);
      float w0 = __shfl(w_l, j, 64),     w1 = __shfl(w_l, j + 1, 64);
      float w2 = __shfl(w_l, j + 2, 64), w3 = __shfl(w_l, j + 3, 64);
      half2v h0 = *(const half2v*)(h + (size_t)u0 * HID + 2 * lane);
      half2v h1 = *(const half2v*)(h + (size_t)u1 * HID + 2 * lane);
      half2v h2 = *(const half2v*)(h + (size_t)u2 * HID + 2 * lane);
      half2v h3 = *(const half2v*)(h + (size_t)u3 * HID + 2 * lane);
      a0 = fmaf(w0, (float)h0[0], a0); a1 = fmaf(w0, (float)h0[1], a1);
      a0 = fmaf(w1, (float)h1[0], a0); a1 = fmaf(w1, (float)h1[1], a1);
      a0 = fmaf(w2, (float)h2[0], a0); a1 = fmaf(w2, (float)h2[1], a1);
      a0 = fmaf(w3, (float)h3[0], a0); a1 = fmaf(w3, (float)h3[1], a1);
    }
  }
  float inv = 1.f / den;
  float x0 = a0 * inv + bias[2 * lane];
  float x1 = a1 * inv + bias[2 * lane + 1];
  half2v o;
  o[0] = (_Float16)((x0 > 0.f) ? x0 : (__expf(x0) - 1.f));
  o[1] = (_Float16)((x1 > 0.f) ? x1 : (__expf(x1) - 1.f));
  *(half2v*)(eh + (size_t)v * HID + 2 * lane) = o;
}

// ---------------- GEMM2+q+GEMM3 fused: embed, q, pred for a 128-row block ----------------
// phase1: embed = eh @ W_enc (MFMA, 4 waves 2x2, wave 64x32)
// epilogue: write embed f32 + LDS f16 tile + q
// phase2: pred = elu(embed @ W_dec) in 4 chunks of 128 cols (wave 64x64)
__global__ __launch_bounds__(256) void k_gemm23q(const _Float16* __restrict__ A,
                                                 const _Float16* __restrict__ Be,
                                                 const _Float16* __restrict__ Bd,
                                                 const float* __restrict__ cent,
                                                 float* __restrict__ embed,
                                                 float* __restrict__ q,
                                                 float* __restrict__ pred, int M) {
  __shared__ char smem[52224];
  _Float16* As  = (_Float16*)smem;             // phase1 A [128][136]
  _Float16* Bs  = (_Float16*)(smem + 34816);   // phase1 B [64][136]
  _Float16* Es  = (_Float16*)smem;             // phase2 embed f16 [128][72]
  _Float16* Bds = (_Float16*)(smem + 18432);   // phase2 W_dec chunk [128][72]
  float*    Cs  = (float*)(smem + 36864);      // centroids [20][64]
  const int tid = threadIdx.x;
  const int lane = tid & 63, wid = tid >> 6;
  const int wrow = (wid >> 1) * 64, wcol = (wid & 1) * 32;   // phase1
  const int wrow2 = (wid >> 1) * 64, wcol2 = (wid & 1) * 64; // phase2
  const int row0 = blockIdx.x * 128;
  const int l31 = lane & 31, lhi = lane >> 5;

#pragma unroll
  for (int c = 0; c < 8; ++c) {         // A: 128 rows x 16 octets
    int idx = tid + c * 256;
    int r = idx >> 4, ko = idx & 15;
    int gr = row0 + r;
    half8 hv = {};
    if (gr < M) hv = *(const half8*)(A + (size_t)gr * HID + ko * 8);
    *(half8*)(&As[r * 136 + ko * 8]) = hv;
  }
#pragma unroll
  for (int c = 0; c < 4; ++c) {         // B: 64 cols x 16 octets
    int idx = tid + c * 256;
    int col = idx >> 4, ko = idx & 15;
    *(half8*)(&Bs[col * 136 + ko * 8]) = *(const half8*)(Be + (size_t)col * HID + ko * 8);
  }
  __syncthreads();

  f32x16 acc[2] = {};
#pragma unroll
  for (int ks = 0; ks < 8; ++ks) {
    half8 a0 = *(half8*)(&As[(wrow + l31) * 136      + ks * 16 + lhi * 8]);
    half8 a1 = *(half8*)(&As[(wrow + 32 + l31) * 136 + ks * 16 + lhi * 8]);
    half8 b0 = *(half8*)(&Bs[(wcol + l31) * 136      + ks * 16 + lhi * 8]);
    acc[0] = __builtin_amdgcn_mfma_f32_32x32x16_f16(a0, b0, acc[0], 0, 0, 0);
    acc[1] = __builtin_amdgcn_mfma_f32_32x32x16_f16(a1, b0, acc[1], 0, 0, 0);
  }
  __syncthreads();                      // done reading As/Bs; repurpose LDS

  // centroids + embed writes (f32 global, f16 LDS)
#pragma unroll
  for (int t = 0; t < 5; ++t) {
    int i = tid + t * 256;
    if (i < KC * OUTD) Cs[i] = cent[i];
  }
#pragma unroll
  for (int mr = 0; mr < 2; ++mr)
#pragma unroll
    for (int r = 0; r < 16; ++r) {
      int lr = wrow + mr * 32 + (r & 3) + 8 * (r >> 2) + 4 * lhi;
      int row = row0 + lr;
      int col = wcol + l31;
      float x = acc[mr][r];
      Es[lr * 72 + col] = (_Float16)x;
      if (row < M) embed[(size_t)row * OUTD + col] = x;
    }
  __syncthreads();

  // stage W_dec chunk 0 while waves 0-1 also do q
#pragma unroll
  for (int cc = 0; cc < 4; ++cc) {
    int idx = tid + cc * 256;
    int col = idx >> 3, ko = idx & 7;
    *(half8*)(&Bds[col * 72 + ko * 8]) = *(const half8*)(Bd + (size_t)col * OUTD + ko * 8);
  }
  if (tid < 128) {
    int row = row0 + tid;
    if (row < M) {
      float accq[KC];
#pragma unroll
      for (int k = 0; k < KC; ++k) accq[k] = 0.f;
#pragma unroll
      for (int d0 = 0; d0 < OUTD; d0 += 8) {
        half8 e8 = *(half8*)(&Es[tid * 72 + d0]);
        float ef[8];
#pragma unroll
        for (int j = 0; j < 8; ++j) ef[j] = (float)e8[j];
#pragma unroll
        for (int k = 0; k < KC; ++k) {
#pragma unroll
          for (int j = 0; j < 8; ++j) {
            float d = ef[j] - Cs[k * OUTD + d0 + j];
            accq[k] = fmaf(d, d, accq[k]);
          }
        }
      }
      float qs = 0.f;
#pragma unroll
      for (int k = 0; k < KC; ++k) {
        accq[k] = 1.f / (1.f + accq[k] + 1e-8f);
        qs += accq[k];
      }
      float inv = 1.f / qs;
      float* qrow = q + (size_t)row * KC;
#pragma unroll
      for (int k0 = 0; k0 < KC; k0 += 4) {
        float4 o = make_float4(accq[k0] * inv, accq[k0 + 1] * inv,
                               accq[k0 + 2] * inv, accq[k0 + 3] * inv);
        *(float4*)(qrow + k0) = o;
      }
    }
  }
  __syncthreads();

  // phase2: 4 chunks of 128 pred cols
  for (int c = 0; c < 4; ++c) {
    f32x16 acc2[2][2] = {};
#pragma unroll
    for (int ks = 0; ks < 4; ++ks) {
      half8 a0 = *(half8*)(&Es[(wrow2 + l31) * 72      + ks * 16 + lhi * 8]);
      half8 a1 = *(half8*)(&Es[(wrow2 + 32 + l31) * 72 + ks * 16 + lhi * 8]);
      half8 b0 = *(half8*)(&Bds[(wcol2 + l31) * 72      + ks * 16 + lhi * 8]);
      half8 b1 = *(half8*)(&Bds[(wcol2 + 32 + l31) * 72 + ks * 16 + lhi * 8]);
      acc2[0][0] = __builtin_amdgcn_mfma_f32_32x32x16_f16(a0, b0, acc2[0][0], 0, 0, 0);
      acc2[0][1] = __builtin_amdgcn_mfma_f32_32x32x16_f16(a0, b1, acc2[0][1], 0, 0, 0);
      acc2[1][0] = __builtin_amdgcn_mfma_f32_32x32x16_f16(a1, b0, acc2[1][0], 0, 0, 0);
      acc2[1][1] = __builtin_amdgcn_mfma_f32_32x32x16_f16(a1, b1, acc2[1][1], 0, 0, 0);
    }
#pragma unroll
    for (int mr = 0; mr < 2; ++mr)
#pragma unroll
      for (int r = 0; r < 16; ++r) {
        int row = row0 + wrow2 + mr * 32 + (r & 3) + 8 * (r >> 2) + 4 * lhi;
        if (row < M) {
#pragma unroll
          for (int nr = 0; nr < 2; ++nr) {
            float x = acc2[mr][nr][r];
            pred[(size_t)row * IN + c * 128 + wcol2 + nr * 32 + l31] =
                (x > 0.f) ? x : (__expf(x) - 1.f);
          }
        }
      }
    if (c < 3) {
      __syncthreads();                  // all waves done reading Bds
      int cb2 = (c + 1) * 128;
#pragma unroll
      for (int cc = 0; cc < 4; ++cc) {
        int idx = tid + cc * 256;
        int col = idx >> 3, ko = idx & 7;
        *(half8*)(&Bds[col * 72 + ko * 8]) = *(const half8*)(Bd + (size_t)(cb2 + col) * OUTD + ko * 8);
      }
      __syncthreads();
    }
  }
}

static inline size_t align16(size_t x) { return (x + 15) & ~(size_t)15; }

extern "C" void kernel_launch(void* const* d_in, const int* in_sizes, int n_in,
                              void* d_out, int out_size, void* d_ws, size_t ws_size,
                              hipStream_t stream) {
  const float* x      = (const float*)d_in[0];
  const float* W_gat  = (const float*)d_in[1];
  const float* attn_l = (const float*)d_in[2];
  const float* attn_r = (const float*)d_in[3];
  const float* bias   = (const float*)d_in[4];
  const float* W_enc  = (const float*)d_in[5];
  const float* W_dec  = (const float*)d_in[6];
  const float* cent   = (const float*)d_in[7];
  const int*   src    = (const int*)d_in[8];
  const int*   dst    = (const int*)d_in[9];

  const int N = in_sizes[0] / IN;
  const int E = in_sizes[8];

  float* out   = (float*)d_out;
  float* embed = out;                            // N x 64
  float* pred  = out + (size_t)N * OUTD;         // N x 512
  float* qout  = pred + (size_t)N * IN;          // N x 20

  char* w = (char*)d_ws;
  size_t off = 0;
  _Float16* h16   = (_Float16*)(w + off); off = align16(off + sizeof(_Float16) * (size_t)N * HID);
  _Float16* eh16  = (_Float16*)(w + off); off = align16(off + sizeof(_Float16) * (size_t)N * HID);
  float* el       = (float*)(w + off);    off = align16(off + sizeof(float) * (size_t)N);
  float* er       = (float*)(w + off);    off = align16(off + sizeof(float) * (size_t)N);
  _Float16* Bt_g  = (_Float16*)(w + off); off = align16(off + sizeof(_Float16) * HID * IN);
  _Float16* Bt_e  = (_Float16*)(w + off); off = align16(off + sizeof(_Float16) * OUTD * HID);
  _Float16* Bt_d  = (_Float16*)(w + off); off = align16(off + sizeof(_Float16) * IN * OUTD);
  int* counts     = (int*)(w + off);      off = align16(off + sizeof(int) * (size_t)N);
  int* rowptr     = (int*)(w + off);      off = align16(off + sizeof(int) * (size_t)(N + 1));
  int* cursor     = (int*)(w + off);      off = align16(off + sizeof(int) * (size_t)N);
  int* colsrc     = (int*)(w + off);      off = align16(off + sizeof(int) * (size_t)E);
  int* bsum       = (int*)(w + off);      off = align16(off + sizeof(int) * 256);

  const int nblk_scan = (N + 511) / 512;
  const int prep_elems = HID * IN + OUTD * HID + IN * OUTD;   // 106496 > N
  const int nblk_prep = (prep_elems > N ? prep_elems : N);

  hipLaunchKernelGGL(k_prep, dim3((nblk_prep + 255) / 256), dim3(256), 0, stream,
                     W_gat, W_enc, W_dec, Bt_g, Bt_e, Bt_d, counts, N);
  hipLaunchKernelGGL(k_gemm1e, dim3((N + 127) / 128), dim3(256), 0, stream,
                     x, Bt_g, attn_l, attn_r, h16, el, er, N);
  hipLaunchKernelGGL(k_hist, dim3((E / 4 + 255) / 256), dim3(256), 0, stream, dst, counts, E);
  hipLaunchKernelGGL(k_scan1, dim3(nblk_scan), dim3(256), 0, stream, counts, bsum, N);
  hipLaunchKernelGGL(k_scan3m, dim3(nblk_scan), dim3(256), 0, stream,
                     counts, bsum, rowptr, cursor, N, nblk_scan);
  hipLaunchKernelGGL(k_fill, dim3((E / 4 + 255) / 256), dim3(256), 0, stream,
                     src, dst, cursor, colsrc, E);
  hipLaunchKernelGGL(k_agg, dim3(((size_t)N * 64 + 255) / 256), dim3(256), 0, stream,
                     h16, el, er, rowptr, counts, colsrc, bias, eh16, N);
  hipLaunchKernelGGL(k_gemm23q, dim3((N + 127) / 128), dim3(256), 0, stream,
                     eh16, Bt_e, Bt_d, cent, embed, qout, pred, N);
}

// Round 7
// 321.032 us; speedup vs baseline: 1.1324x; 1.1324x over previous
//
#include <hip/hip_runtime.h>
#include <math.h>

constexpr int IN   = 512;
constexpr int HID  = 128;
constexpr int OUTD = 64;
constexpr int KC   = 20;
#define LRELU_SLOPE 0.2f

typedef _Float16 half8 __attribute__((ext_vector_type(8)));
typedef _Float16 half2v __attribute__((ext_vector_type(2)));
typedef float f32x16 __attribute__((ext_vector_type(16)));

__device__ __forceinline__ float warp_sum(float v) {
#pragma unroll
  for (int o = 32; o > 0; o >>= 1) v += __shfl_xor(v, o, 64);
  return v;
}

// ---------------- prep: transpose+convert weights to f16 [col][K]; zero counts ----------------
__global__ __launch_bounds__(256) void k_prep(const float* __restrict__ Wg,
                                              const float* __restrict__ We,
                                              const float* __restrict__ Wd,
                                              _Float16* Bg, _Float16* Be, _Float16* Bd,
                                              int* counts, int N) {
  int i = blockIdx.x * 256 + threadIdx.x;
  if (i < N) counts[i] = 0;
  if (i < HID * IN) {                 // Bg[c][k] = Wg[k][c]
    int c = i >> 9, k = i & 511;
    Bg[i] = (_Float16)Wg[(size_t)k * HID + c];
    return;
  }
  i -= HID * IN;
  if (i < OUTD * HID) {               // Be[c][k] = We[k][c]
    int c = i >> 7, k = i & 127;
    Be[i] = (_Float16)We[(size_t)k * OUTD + c];
    return;
  }
  i -= OUTD * HID;
  if (i < IN * OUTD) {                // Bd[c][k] = Wd[k][c]
    int c = i >> 6, k = i & 63;
    Bd[i] = (_Float16)Wd[(size_t)k * IN + c];
  }
}

// ---------------- GEMM1: h(f16) = x @ W_gat + fused el/er (LDS, shuffle-free) ----------------
// block 128x128, BK=64, 4 waves 2x2, wave tile 64x64
__global__ __launch_bounds__(256) void k_gemm1e(const float* __restrict__ A,
                                                const _Float16* __restrict__ Bt,
                                                const float* __restrict__ al,
                                                const float* __restrict__ ar,
                                                _Float16* __restrict__ H,
                                                float* __restrict__ el,
                                                float* __restrict__ er, int M) {
  __shared__ char smem[36864];
  _Float16* As = (_Float16*)smem;              // [128][72]
  _Float16* Bs = (_Float16*)(smem + 18432);    // [128][72]
  _Float16* Hs = (_Float16*)smem;              // epilogue: h tile [128][136] = 34816 B
  float*    als = (float*)(smem + 34816);      // 512 B
  float*    ars = (float*)(smem + 35328);      // 512 B
  const int tid = threadIdx.x;
  const int lane = tid & 63, wid = tid >> 6;
  const int wrow = (wid >> 1) * 64, wcol = (wid & 1) * 64;
  const int row0 = blockIdx.x * 128;
  const int l31 = lane & 31, lhi = lane >> 5;

  f32x16 acc[2][2] = {};

  for (int k0 = 0; k0 < IN; k0 += 64) {
#pragma unroll
    for (int c = 0; c < 4; ++c) {       // A: 128 rows x 8 k-octets
      int idx = tid + c * 256;
      int r = idx >> 3, ko = idx & 7;
      int gr = row0 + r;
      float4 v0 = make_float4(0.f, 0.f, 0.f, 0.f), v1 = v0;
      if (gr < M) {
        const float* p = A + (size_t)gr * IN + k0 + ko * 8;
        v0 = *(const float4*)p;
        v1 = *(const float4*)(p + 4);
      }
      half8 hv;
      hv[0] = (_Float16)v0.x; hv[1] = (_Float16)v0.y; hv[2] = (_Float16)v0.z; hv[3] = (_Float16)v0.w;
      hv[4] = (_Float16)v1.x; hv[5] = (_Float16)v1.y; hv[6] = (_Float16)v1.z; hv[7] = (_Float16)v1.w;
      *(half8*)(&As[r * 72 + ko * 8]) = hv;
    }
#pragma unroll
    for (int c = 0; c < 4; ++c) {       // B: 128 cols x 8 k-octets ([col][K] f16)
      int idx = tid + c * 256;
      int col = idx >> 3, ko = idx & 7;
      *(half8*)(&Bs[col * 72 + ko * 8]) = *(const half8*)(Bt + (size_t)col * IN + k0 + ko * 8);
    }
    __syncthreads();
#pragma unroll
    for (int ks = 0; ks < 4; ++ks) {
      half8 a0 = *(half8*)(&As[(wrow + l31) * 72      + ks * 16 + lhi * 8]);
      half8 a1 = *(half8*)(&As[(wrow + 32 + l31) * 72 + ks * 16 + lhi * 8]);
      half8 b0 = *(half8*)(&Bs[(wcol + l31) * 72      + ks * 16 + lhi * 8]);
      half8 b1 = *(half8*)(&Bs[(wcol + 32 + l31) * 72 + ks * 16 + lhi * 8]);
      acc[0][0] = __builtin_amdgcn_mfma_f32_32x32x16_f16(a0, b0, acc[0][0], 0, 0, 0);
      acc[0][1] = __builtin_amdgcn_mfma_f32_32x32x16_f16(a0, b1, acc[0][1], 0, 0, 0);
      acc[1][0] = __builtin_amdgcn_mfma_f32_32x32x16_f16(a1, b0, acc[1][0], 0, 0, 0);
      acc[1][1] = __builtin_amdgcn_mfma_f32_32x32x16_f16(a1, b1, acc[1][1], 0, 0, 0);
    }
    __syncthreads();
  }
  // epilogue: stage al/ar, write h to global + LDS tile
  if (tid < 128) als[tid] = al[tid];
  else ars[tid - 128] = ar[tid - 128];
#pragma unroll
  for (int mr = 0; mr < 2; ++mr)
#pragma unroll
    for (int r = 0; r < 16; ++r) {
      int lr = wrow + mr * 32 + (r & 3) + 8 * (r >> 2) + 4 * lhi;
      int row = row0 + lr;
#pragma unroll
      for (int nr = 0; nr < 2; ++nr) {
        _Float16 hv = (_Float16)acc[mr][nr][r];
        Hs[lr * 136 + wcol + nr * 32 + l31] = hv;
        if (row < M) H[(size_t)row * HID + wcol + nr * 32 + l31] = hv;
      }
    }
  __syncthreads();
  if (tid < 128) {
    int row = row0 + tid;
    if (row < M) {
      float sl = 0.f, sr = 0.f;
#pragma unroll
      for (int c8 = 0; c8 < 16; ++c8) {
        half8 hv = *(half8*)(&Hs[tid * 136 + c8 * 8]);
#pragma unroll
        for (int j = 0; j < 8; ++j) {
          float hf = (float)hv[j];
          sl = fmaf(hf, als[c8 * 8 + j], sl);
          sr = fmaf(hf, ars[c8 * 8 + j], sr);
        }
      }
      el[row] = sl;
      er[row] = sr;
    }
  }
}

// ---------------- CSR build ----------------
__global__ void k_hist(const int* __restrict__ dst, int* counts, int E) {
  int i = (blockIdx.x * blockDim.x + threadIdx.x) * 4;
  if (i + 4 <= E) {
    int4 d = *(const int4*)(dst + i);
    atomicAdd(&counts[d.x], 1); atomicAdd(&counts[d.y], 1);
    atomicAdd(&counts[d.z], 1); atomicAdd(&counts[d.w], 1);
  } else {
    for (; i < E; ++i) atomicAdd(&counts[dst[i]], 1);
  }
}

__global__ __launch_bounds__(256) void k_scan1(const int* __restrict__ counts, int* bsum, int N) {
  __shared__ int s[256];
  int b = blockIdx.x, t = threadIdx.x;
  int i0 = b * 512 + t * 2;
  int v = 0;
  if (i0 < N) v += counts[i0];
  if (i0 + 1 < N) v += counts[i0 + 1];
  s[t] = v;
  __syncthreads();
  for (int off = 128; off > 0; off >>= 1) {
    if (t < off) s[t] += s[t + off];
    __syncthreads();
  }
  if (t == 0) bsum[b] = s[0];
}

// scan2 merged: each block redundantly prefix-sums bsum (nblk<=256)
__global__ __launch_bounds__(256) void k_scan3m(const int* __restrict__ counts,
                                                const int* __restrict__ bsum,
                                                int* rowptr, int* cursor, int N, int nblk) {
  __shared__ int sb[256];
  __shared__ int s[256];
  int b = blockIdx.x, t = threadIdx.x;
  int v = (t < nblk) ? bsum[t] : 0;
  sb[t] = v;
  __syncthreads();
#pragma unroll
  for (int off = 1; off < 256; off <<= 1) {
    int u = 0;
    if (t >= off) u = sb[t - off];
    __syncthreads();
    sb[t] += u;
    __syncthreads();
  }
  int boffb = (b == 0) ? 0 : sb[b - 1];

  int i0 = b * 512 + t * 2;
  int c0 = (i0 < N) ? counts[i0] : 0;
  int c1 = (i0 + 1 < N) ? counts[i0 + 1] : 0;
  int tsum = c0 + c1;
  s[t] = tsum;
  __syncthreads();
#pragma unroll
  for (int off = 1; off < 256; off <<= 1) {
    int u = 0;
    if (t >= off) u = s[t - off];
    __syncthreads();
    s[t] += u;
    __syncthreads();
  }
  int base = boffb + s[t] - tsum;
  if (i0 < N)     { rowptr[i0] = base;          cursor[i0] = base; }
  if (i0 + 1 < N) { rowptr[i0 + 1] = base + c0; cursor[i0 + 1] = base + c0; }
}

__global__ void k_fill(const int* __restrict__ src, const int* __restrict__ dst,
                       int* cursor, int* colsrc, int E) {
  int i = (blockIdx.x * blockDim.x + threadIdx.x) * 4;
  if (i + 4 <= E) {
    int4 sv = *(const int4*)(src + i);
    int4 dv = *(const int4*)(dst + i);
    colsrc[atomicAdd(&cursor[dv.x], 1)] = sv.x;
    colsrc[atomicAdd(&cursor[dv.y], 1)] = sv.y;
    colsrc[atomicAdd(&cursor[dv.z], 1)] = sv.z;
    colsrc[atomicAdd(&cursor[dv.w], 1)] = sv.w;
  } else {
    for (; i < E; ++i) {
      int d = dst[i];
      colsrc[atomicAdd(&cursor[d], 1)] = src[i];
    }
  }
}

// ---------------- edge softmax + aggregation + elu -> eh(f16) ----------------
__global__ __launch_bounds__(256) void k_agg(const _Float16* __restrict__ h,
                                             const float* __restrict__ el,
                                             const float* __restrict__ er,
                                             const int* __restrict__ rowptr,
                                             const int* __restrict__ counts,
                                             const int* __restrict__ colsrc,
                                             const float* __restrict__ bias,
                                             _Float16* __restrict__ eh, int N) {
  int g = blockIdx.x * blockDim.x + threadIdx.x;
  int v = g >> 6, lane = g & 63;
  if (v >= N) return;
  int start = rowptr[v], deg = counts[v];
  float erv = er[v];

  float a0 = 0.f, a1 = 0.f, den = 0.f;
  for (int base = 0; base < deg; base += 64) {
    int cnt = deg - base; if (cnt > 64) cnt = 64;
    int u_l = 0; float w_l = 0.f;
    if (lane < cnt) {
      u_l = colsrc[start + base + lane];
      float e = el[u_l] + erv;
      e = (e > 0.f) ? e : LRELU_SLOPE * e;
      w_l = __expf(e);                  // softmax shift-invariant; e bounded
    }
    den += warp_sum(w_l);
    int cntR = (cnt + 3) & ~3;
    for (int j = 0; j < cntR; j += 4) {
      int   u0 = __shfl(u_l, j, 64),     u1 = __shfl(u_l, j + 1, 64);
      int   u2 = __shfl(u_l, j + 2, 64), u3 = __shfl(u_l, j + 3, 64);
      float w0 = __shfl(w_l, j, 64),     w1 = __shfl(w_l, j + 1, 64);
      float w2 = __shfl(w_l, j + 2, 64), w3 = __shfl(w_l, j + 3, 64);
      half2v h0 = *(const half2v*)(h + (size_t)u0 * HID + 2 * lane);
      half2v h1 = *(const half2v*)(h + (size_t)u1 * HID + 2 * lane);
      half2v h2 = *(const half2v*)(h + (size_t)u2 * HID + 2 * lane);
      half2v h3 = *(const half2v*)(h + (size_t)u3 * HID + 2 * lane);
      a0 = fmaf(w0, (float)h0[0], a0); a1 = fmaf(w0, (float)h0[1], a1);
      a0 = fmaf(w1, (float)h1[0], a0); a1 = fmaf(w1, (float)h1[1], a1);
      a0 = fmaf(w2, (float)h2[0], a0); a1 = fmaf(w2, (float)h2[1], a1);
      a0 = fmaf(w3, (float)h3[0], a0); a1 = fmaf(w3, (float)h3[1], a1);
    }
  }
  float inv = 1.f / den;
  float x0 = a0 * inv + bias[2 * lane];
  float x1 = a1 * inv + bias[2 * lane + 1];
  half2v o;
  o[0] = (_Float16)((x0 > 0.f) ? x0 : (__expf(x0) - 1.f));
  o[1] = (_Float16)((x1 > 0.f) ? x1 : (__expf(x1) - 1.f));
  *(half2v*)(eh + (size_t)v * HID + 2 * lane) = o;
}

// ---------------- GEMM2 + q: embed = eh @ W_enc, then DEC assignment ----------------
__global__ __launch_bounds__(256) void k_gemm2q(const _Float16* __restrict__ A,
                                                const _Float16* __restrict__ Bt,
                                                const float* __restrict__ cent,
                                                float* __restrict__ C,
                                                _Float16* __restrict__ C16,
                                                float* __restrict__ q, int M) {
  __shared__ _Float16 As[128 * 136];   // 34816 B; reused as f32 [128][68]
  __shared__ _Float16 Bs[64 * 136];    // 17408 B; reused as f32 cent [20][64]
  const int tid = threadIdx.x;
  const int lane = tid & 63, wid = tid >> 6;
  const int wrow = (wid >> 1) * 64, wcol = (wid & 1) * 32;
  const int row0 = blockIdx.x * 128;
  const int l31 = lane & 31, lhi = lane >> 5;

#pragma unroll
  for (int c = 0; c < 8; ++c) {         // A: 128 rows x 16 octets
    int idx = tid + c * 256;
    int r = idx >> 4, ko = idx & 15;
    int gr = row0 + r;
    half8 hv = {};
    if (gr < M) hv = *(const half8*)(A + (size_t)gr * HID + ko * 8);
    *(half8*)(&As[r * 136 + ko * 8]) = hv;
  }
#pragma unroll
  for (int c = 0; c < 4; ++c) {         // B: 64 cols x 16 octets
    int idx = tid + c * 256;
    int col = idx >> 4, ko = idx & 15;
    *(half8*)(&Bs[col * 136 + ko * 8]) = *(const half8*)(Bt + (size_t)col * HID + ko * 8);
  }
  __syncthreads();

  f32x16 acc[2] = {};
#pragma unroll
  for (int ks = 0; ks < 8; ++ks) {
    half8 a0 = *(half8*)(&As[(wrow + l31) * 136      + ks * 16 + lhi * 8]);
    half8 a1 = *(half8*)(&As[(wrow + 32 + l31) * 136 + ks * 16 + lhi * 8]);
    half8 b0 = *(half8*)(&Bs[(wcol + l31) * 136      + ks * 16 + lhi * 8]);
    acc[0] = __builtin_amdgcn_mfma_f32_32x32x16_f16(a0, b0, acc[0], 0, 0, 0);
    acc[1] = __builtin_amdgcn_mfma_f32_32x32x16_f16(a1, b0, acc[1], 0, 0, 0);
  }
  __syncthreads();                      // As/Bs ds_reads done; repurpose

  float* Es = (float*)As;               // [128][68]
  float* Cs = (float*)Bs;               // [20][64]
#pragma unroll
  for (int t = 0; t < 5; ++t) {
    int i = tid + t * 256;
    if (i < KC * OUTD) Cs[i] = cent[i];
  }
#pragma unroll
  for (int mr = 0; mr < 2; ++mr)
#pragma unroll
    for (int r = 0; r < 16; ++r) {
      int lr = wrow + mr * 32 + (r & 3) + 8 * (r >> 2) + 4 * lhi;
      int row = row0 + lr;
      int col = wcol + l31;
      float x = acc[mr][r];
      Es[lr * 68 + col] = x;
      if (row < M) {
        C[(size_t)row * OUTD + col] = x;
        C16[(size_t)row * OUTD + col] = (_Float16)x;
      }
    }
  __syncthreads();

  if (tid < 128) {
    int row = row0 + tid;
    if (row < M) {
      const float* erow = &Es[tid * 68];
      float accq[KC];
#pragma unroll
      for (int k = 0; k < KC; ++k) accq[k] = 0.f;
#pragma unroll
      for (int d0 = 0; d0 < OUTD; d0 += 4) {
        float4 e4 = *(const float4*)(erow + d0);
#pragma unroll
        for (int k = 0; k < KC; ++k) {
          float4 c4 = *(const float4*)(&Cs[k * OUTD + d0]);
          float dx = e4.x - c4.x, dy = e4.y - c4.y, dz = e4.z - c4.z, dw = e4.w - c4.w;
          accq[k] = fmaf(dx, dx, fmaf(dy, dy, fmaf(dz, dz, fmaf(dw, dw, accq[k]))));
        }
      }
      float qs = 0.f;
#pragma unroll
      for (int k = 0; k < KC; ++k) {
        accq[k] = 1.f / (1.f + accq[k] + 1e-8f);
        qs += accq[k];
      }
      float inv = 1.f / qs;
      float* qrow = q + (size_t)row * KC;
#pragma unroll
      for (int k0 = 0; k0 < KC; k0 += 4) {
        float4 o = make_float4(accq[k0] * inv, accq[k0 + 1] * inv,
                               accq[k0 + 2] * inv, accq[k0 + 3] * inv);
        *(float4*)(qrow + k0) = o;
      }
    }
  }
}

// ---------------- GEMM3: pred = elu(embed @ W_dec)  (M x 64)(64 x 512), MFMA ----------------
// block 128x128 (grid.y=4), 4 waves 2x2, wave 64x64; 36KB LDS -> 4 blocks/CU
__global__ __launch_bounds__(256) void k_gemm3(const _Float16* __restrict__ A,
                                               const _Float16* __restrict__ Bt,
                                               float* __restrict__ C, int M) {
  __shared__ _Float16 As[128 * 72];
  __shared__ _Float16 Bs[128 * 72];
  const int tid = threadIdx.x;
  const int lane = tid & 63, wid = tid >> 6;
  const int wrow = (wid >> 1) * 64, wcol = (wid & 1) * 64;
  const int row0 = blockIdx.x * 128;
  const int cb = blockIdx.y * 128;
  const int l31 = lane & 31, lhi = lane >> 5;

#pragma unroll
  for (int c = 0; c < 4; ++c) {         // A: 128 rows x 8 octets
    int idx = tid + c * 256;
    int r = idx >> 3, ko = idx & 7;
    int gr = row0 + r;
    half8 hv = {};
    if (gr < M) hv = *(const half8*)(A + (size_t)gr * OUTD + ko * 8);
    *(half8*)(&As[r * 72 + ko * 8]) = hv;
  }
#pragma unroll
  for (int c = 0; c < 4; ++c) {         // B: 128 cols x 8 octets
    int idx = tid + c * 256;
    int col = idx >> 3, ko = idx & 7;
    *(half8*)(&Bs[col * 72 + ko * 8]) = *(const half8*)(Bt + (size_t)(cb + col) * OUTD + ko * 8);
  }
  __syncthreads();

  f32x16 acc[2][2] = {};
#pragma unroll
  for (int ks = 0; ks < 4; ++ks) {
    half8 a0 = *(half8*)(&As[(wrow + l31) * 72      + ks * 16 + lhi * 8]);
    half8 a1 = *(half8*)(&As[(wrow + 32 + l31) * 72 + ks * 16 + lhi * 8]);
    half8 b0 = *(half8*)(&Bs[(wcol + l31) * 72      + ks * 16 + lhi * 8]);
    half8 b1 = *(half8*)(&Bs[(wcol + 32 + l31) * 72 + ks * 16 + lhi * 8]);
    acc[0][0] = __builtin_amdgcn_mfma_f32_32x32x16_f16(a0, b0, acc[0][0], 0, 0, 0);
    acc[0][1] = __builtin_amdgcn_mfma_f32_32x32x16_f16(a0, b1, acc[0][1], 0, 0, 0);
    acc[1][0] = __builtin_amdgcn_mfma_f32_32x32x16_f16(a1, b0, acc[1][0], 0, 0, 0);
    acc[1][1] = __builtin_amdgcn_mfma_f32_32x32x16_f16(a1, b1, acc[1][1], 0, 0, 0);
  }
#pragma unroll
  for (int mr = 0; mr < 2; ++mr)
#pragma unroll
    for (int r = 0; r < 16; ++r) {
      int row = row0 + wrow + mr * 32 + (r & 3) + 8 * (r >> 2) + 4 * lhi;
      if (row < M) {
#pragma unroll
        for (int nr = 0; nr < 2; ++nr) {
          float x = acc[mr][nr][r];
          C[(size_t)row * IN + cb + wcol + nr * 32 + l31] =
              (x > 0.f) ? x : (__expf(x) - 1.f);
        }
      }
    }
}

static inline size_t align16(size_t x) { return (x + 15) & ~(size_t)15; }

extern "C" void kernel_launch(void* const* d_in, const int* in_sizes, int n_in,
                              void* d_out, int out_size, void* d_ws, size_t ws_size,
                              hipStream_t stream) {
  const float* x      = (const float*)d_in[0];
  const float* W_gat  = (const float*)d_in[1];
  const float* attn_l = (const float*)d_in[2];
  const float* attn_r = (const float*)d_in[3];
  const float* bias   = (const float*)d_in[4];
  const float* W_enc  = (const float*)d_in[5];
  const float* W_dec  = (const float*)d_in[6];
  const float* cent   = (const float*)d_in[7];
  const int*   src    = (const int*)d_in[8];
  const int*   dst    = (const int*)d_in[9];

  const int N = in_sizes[0] / IN;
  const int E = in_sizes[8];

  float* out   = (float*)d_out;
  float* embed = out;                            // N x 64
  float* pred  = out + (size_t)N * OUTD;         // N x 512
  float* qout  = pred + (size_t)N * IN;          // N x 20

  char* w = (char*)d_ws;
  size_t off = 0;
  _Float16* h16   = (_Float16*)(w + off); off = align16(off + sizeof(_Float16) * (size_t)N * HID);
  _Float16* eh16  = (_Float16*)(w + off); off = align16(off + sizeof(_Float16) * (size_t)N * HID);
  _Float16* emb16 = (_Float16*)(w + off); off = align16(off + sizeof(_Float16) * (size_t)N * OUTD);
  float* el       = (float*)(w + off);    off = align16(off + sizeof(float) * (size_t)N);
  float* er       = (float*)(w + off);    off = align16(off + sizeof(float) * (size_t)N);
  _Float16* Bt_g  = (_Float16*)(w + off); off = align16(off + sizeof(_Float16) * HID * IN);
  _Float16* Bt_e  = (_Float16*)(w + off); off = align16(off + sizeof(_Float16) * OUTD * HID);
  _Float16* Bt_d  = (_Float16*)(w + off); off = align16(off + sizeof(_Float16) * IN * OUTD);
  int* counts     = (int*)(w + off);      off = align16(off + sizeof(int) * (size_t)N);
  int* rowptr     = (int*)(w + off);      off = align16(off + sizeof(int) * (size_t)(N + 1));
  int* cursor     = (int*)(w + off);      off = align16(off + sizeof(int) * (size_t)N);
  int* colsrc     = (int*)(w + off);      off = align16(off + sizeof(int) * (size_t)E);
  int* bsum       = (int*)(w + off);      off = align16(off + sizeof(int) * 256);

  const int nblk_scan = (N + 511) / 512;
  const int prep_elems = HID * IN + OUTD * HID + IN * OUTD;   // 106496 > N
  const int nblk_prep = (prep_elems > N ? prep_elems : N);

  hipLaunchKernelGGL(k_prep, dim3((nblk_prep + 255) / 256), dim3(256), 0, stream,
                     W_gat, W_enc, W_dec, Bt_g, Bt_e, Bt_d, counts, N);
  hipLaunchKernelGGL(k_gemm1e, dim3((N + 127) / 128), dim3(256), 0, stream,
                     x, Bt_g, attn_l, attn_r, h16, el, er, N);
  hipLaunchKernelGGL(k_hist, dim3((E / 4 + 255) / 256), dim3(256), 0, stream, dst, counts, E);
  hipLaunchKernelGGL(k_scan1, dim3(nblk_scan), dim3(256), 0, stream, counts, bsum, N);
  hipLaunchKernelGGL(k_scan3m, dim3(nblk_scan), dim3(256), 0, stream,
                     counts, bsum, rowptr, cursor, N, nblk_scan);
  hipLaunchKernelGGL(k_fill, dim3((E / 4 + 255) / 256), dim3(256), 0, stream,
                     src, dst, cursor, colsrc, E);
  hipLaunchKernelGGL(k_agg, dim3(((size_t)N * 64 + 255) / 256), dim3(256), 0, stream,
                     h16, el, er, rowptr, counts, colsrc, bias, eh16, N);
  hipLaunchKernelGGL(k_gemm2q, dim3((N + 127) / 128), dim3(256), 0, stream,
                     eh16, Bt_e, cent, embed, emb16, qout, N);
  hipLaunchKernelGGL(k_gemm3, dim3((N + 127) / 128, 4), dim3(256), 0, stream, emb16, Bt_d, pred, N);
}

// Round 8
// 291.315 us; speedup vs baseline: 1.2479x; 1.1020x over previous
//
#include <hip/hip_runtime.h>
#include <math.h>

constexpr int IN   = 512;
constexpr int HID  = 128;
constexpr int OUTD = 64;
constexpr int KC   = 20;
#define LRELU_SLOPE 0.2f

typedef _Float16 half8 __attribute__((ext_vector_type(8)));
typedef _Float16 half2v __attribute__((ext_vector_type(2)));
typedef float f32x16 __attribute__((ext_vector_type(16)));

__device__ __forceinline__ float warp_sum(float v) {
#pragma unroll
  for (int o = 32; o > 0; o >>= 1) v += __shfl_xor(v, o, 64);
  return v;
}
__device__ __forceinline__ float group_sum16(float v) {
#pragma unroll
  for (int o = 8; o > 0; o >>= 1) v += __shfl_xor(v, o, 64);
  return v;
}

// ---------------- prep: transpose+convert weights to f16 [col][K]; zero counts ----------------
__global__ __launch_bounds__(256) void k_prep(const float* __restrict__ Wg,
                                              const float* __restrict__ We,
                                              const float* __restrict__ Wd,
                                              _Float16* Bg, _Float16* Be, _Float16* Bd,
                                              int* counts, int N) {
  int i = blockIdx.x * 256 + threadIdx.x;
  if (i < N) counts[i] = 0;
  if (i < HID * IN) {                 // Bg[c][k] = Wg[k][c]
    int c = i >> 9, k = i & 511;
    Bg[i] = (_Float16)Wg[(size_t)k * HID + c];
    return;
  }
  i -= HID * IN;
  if (i < OUTD * HID) {               // Be[c][k] = We[k][c]
    int c = i >> 7, k = i & 127;
    Be[i] = (_Float16)We[(size_t)k * OUTD + c];
    return;
  }
  i -= OUTD * HID;
  if (i < IN * OUTD) {                // Bd[c][k] = Wd[k][c]
    int c = i >> 6, k = i & 63;
    Bd[i] = (_Float16)Wd[(size_t)k * IN + c];
  }
}

// ---------------- GEMM1: h(f16) = x @ W_gat + fused el/er (LDS, shuffle-free) ----------------
__global__ __launch_bounds__(256) void k_gemm1e(const float* __restrict__ A,
                                                const _Float16* __restrict__ Bt,
                                                const float* __restrict__ al,
                                                const float* __restrict__ ar,
                                                _Float16* __restrict__ H,
                                                float* __restrict__ el,
                                                float* __restrict__ er, int M) {
  __shared__ char smem[36864];
  _Float16* As = (_Float16*)smem;              // [128][72]
  _Float16* Bs = (_Float16*)(smem + 18432);    // [128][72]
  _Float16* Hs = (_Float16*)smem;              // epilogue: h tile [128][136]
  float*    als = (float*)(smem + 34816);
  float*    ars = (float*)(smem + 35328);
  const int tid = threadIdx.x;
  const int lane = tid & 63, wid = tid >> 6;
  const int wrow = (wid >> 1) * 64, wcol = (wid & 1) * 64;
  const int row0 = blockIdx.x * 128;
  const int l31 = lane & 31, lhi = lane >> 5;

  f32x16 acc[2][2] = {};

  for (int k0 = 0; k0 < IN; k0 += 64) {
#pragma unroll
    for (int c = 0; c < 4; ++c) {
      int idx = tid + c * 256;
      int r = idx >> 3, ko = idx & 7;
      int gr = row0 + r;
      float4 v0 = make_float4(0.f, 0.f, 0.f, 0.f), v1 = v0;
      if (gr < M) {
        const float* p = A + (size_t)gr * IN + k0 + ko * 8;
        v0 = *(const float4*)p;
        v1 = *(const float4*)(p + 4);
      }
      half8 hv;
      hv[0] = (_Float16)v0.x; hv[1] = (_Float16)v0.y; hv[2] = (_Float16)v0.z; hv[3] = (_Float16)v0.w;
      hv[4] = (_Float16)v1.x; hv[5] = (_Float16)v1.y; hv[6] = (_Float16)v1.z; hv[7] = (_Float16)v1.w;
      *(half8*)(&As[r * 72 + ko * 8]) = hv;
    }
#pragma unroll
    for (int c = 0; c < 4; ++c) {
      int idx = tid + c * 256;
      int col = idx >> 3, ko = idx & 7;
      *(half8*)(&Bs[col * 72 + ko * 8]) = *(const half8*)(Bt + (size_t)col * IN + k0 + ko * 8);
    }
    __syncthreads();
#pragma unroll
    for (int ks = 0; ks < 4; ++ks) {
      half8 a0 = *(half8*)(&As[(wrow + l31) * 72      + ks * 16 + lhi * 8]);
      half8 a1 = *(half8*)(&As[(wrow + 32 + l31) * 72 + ks * 16 + lhi * 8]);
      half8 b0 = *(half8*)(&Bs[(wcol + l31) * 72      + ks * 16 + lhi * 8]);
      half8 b1 = *(half8*)(&Bs[(wcol + 32 + l31) * 72 + ks * 16 + lhi * 8]);
      acc[0][0] = __builtin_amdgcn_mfma_f32_32x32x16_f16(a0, b0, acc[0][0], 0, 0, 0);
      acc[0][1] = __builtin_amdgcn_mfma_f32_32x32x16_f16(a0, b1, acc[0][1], 0, 0, 0);
      acc[1][0] = __builtin_amdgcn_mfma_f32_32x32x16_f16(a1, b0, acc[1][0], 0, 0, 0);
      acc[1][1] = __builtin_amdgcn_mfma_f32_32x32x16_f16(a1, b1, acc[1][1], 0, 0, 0);
    }
    __syncthreads();
  }
  if (tid < 128) als[tid] = al[tid];
  else ars[tid - 128] = ar[tid - 128];
#pragma unroll
  for (int mr = 0; mr < 2; ++mr)
#pragma unroll
    for (int r = 0; r < 16; ++r) {
      int lr = wrow + mr * 32 + (r & 3) + 8 * (r >> 2) + 4 * lhi;
      int row = row0 + lr;
#pragma unroll
      for (int nr = 0; nr < 2; ++nr) {
        _Float16 hv = (_Float16)acc[mr][nr][r];
        Hs[lr * 136 + wcol + nr * 32 + l31] = hv;
        if (row < M) H[(size_t)row * HID + wcol + nr * 32 + l31] = hv;
      }
    }
  __syncthreads();
  if (tid < 128) {
    int row = row0 + tid;
    if (row < M) {
      float sl = 0.f, sr = 0.f;
#pragma unroll
      for (int c8 = 0; c8 < 16; ++c8) {
        half8 hv = *(half8*)(&Hs[tid * 136 + c8 * 8]);
#pragma unroll
        for (int j = 0; j < 8; ++j) {
          float hf = (float)hv[j];
          sl = fmaf(hf, als[c8 * 8 + j], sl);
          sr = fmaf(hf, ars[c8 * 8 + j], sr);
        }
      }
      el[row] = sl;
      er[row] = sr;
    }
  }
}

// ---------------- CSR build ----------------
__global__ void k_hist(const int* __restrict__ dst, int* counts, int E) {
  int i = (blockIdx.x * blockDim.x + threadIdx.x) * 4;
  if (i + 4 <= E) {
    int4 d = *(const int4*)(dst + i);
    atomicAdd(&counts[d.x], 1); atomicAdd(&counts[d.y], 1);
    atomicAdd(&counts[d.z], 1); atomicAdd(&counts[d.w], 1);
  } else {
    for (; i < E; ++i) atomicAdd(&counts[dst[i]], 1);
  }
}

__global__ __launch_bounds__(256) void k_scan1(const int* __restrict__ counts, int* bsum, int N) {
  __shared__ int s[256];
  int b = blockIdx.x, t = threadIdx.x;
  int i0 = b * 512 + t * 2;
  int v = 0;
  if (i0 < N) v += counts[i0];
  if (i0 + 1 < N) v += counts[i0 + 1];
  s[t] = v;
  __syncthreads();
  for (int off = 128; off > 0; off >>= 1) {
    if (t < off) s[t] += s[t + off];
    __syncthreads();
  }
  if (t == 0) bsum[b] = s[0];
}

__global__ __launch_bounds__(256) void k_scan3m(const int* __restrict__ counts,
                                                const int* __restrict__ bsum,
                                                int* rowptr, int* cursor, int N, int nblk) {
  __shared__ int sb[256];
  __shared__ int s[256];
  int b = blockIdx.x, t = threadIdx.x;
  int v = (t < nblk) ? bsum[t] : 0;
  sb[t] = v;
  __syncthreads();
#pragma unroll
  for (int off = 1; off < 256; off <<= 1) {
    int u = 0;
    if (t >= off) u = sb[t - off];
    __syncthreads();
    sb[t] += u;
    __syncthreads();
  }
  int boffb = (b == 0) ? 0 : sb[b - 1];

  int i0 = b * 512 + t * 2;
  int c0 = (i0 < N) ? counts[i0] : 0;
  int c1 = (i0 + 1 < N) ? counts[i0 + 1] : 0;
  int tsum = c0 + c1;
  s[t] = tsum;
  __syncthreads();
#pragma unroll
  for (int off = 1; off < 256; off <<= 1) {
    int u = 0;
    if (t >= off) u = s[t - off];
    __syncthreads();
    s[t] += u;
    __syncthreads();
  }
  int base = boffb + s[t] - tsum;
  if (i0 < N)     { rowptr[i0] = base;          cursor[i0] = base; }
  if (i0 + 1 < N) { rowptr[i0 + 1] = base + c0; cursor[i0 + 1] = base + c0; }
}

// fill + per-edge attention weight precompute; packed scatter int2{src, w_bits}
__global__ void k_fill(const int* __restrict__ src, const int* __restrict__ dst,
                       const float* __restrict__ el, const float* __restrict__ er,
                       int* cursor, int2* colsw, int E) {
  int i = (blockIdx.x * blockDim.x + threadIdx.x) * 4;
  if (i + 4 <= E) {
    int4 sv = *(const int4*)(src + i);
    int4 dv = *(const int4*)(dst + i);
    float e0 = el[sv.x] + er[dv.x]; e0 = (e0 > 0.f) ? e0 : LRELU_SLOPE * e0;
    float e1 = el[sv.y] + er[dv.y]; e1 = (e1 > 0.f) ? e1 : LRELU_SLOPE * e1;
    float e2 = el[sv.z] + er[dv.z]; e2 = (e2 > 0.f) ? e2 : LRELU_SLOPE * e2;
    float e3 = el[sv.w] + er[dv.w]; e3 = (e3 > 0.f) ? e3 : LRELU_SLOPE * e3;
    float w0 = __expf(e0), w1 = __expf(e1), w2 = __expf(e2), w3 = __expf(e3);
    colsw[atomicAdd(&cursor[dv.x], 1)] = make_int2(sv.x, __float_as_int(w0));
    colsw[atomicAdd(&cursor[dv.y], 1)] = make_int2(sv.y, __float_as_int(w1));
    colsw[atomicAdd(&cursor[dv.z], 1)] = make_int2(sv.z, __float_as_int(w2));
    colsw[atomicAdd(&cursor[dv.w], 1)] = make_int2(sv.w, __float_as_int(w3));
  } else {
    for (; i < E; ++i) {
      int s = src[i], d = dst[i];
      float e = el[s] + er[d]; e = (e > 0.f) ? e : LRELU_SLOPE * e;
      colsw[atomicAdd(&cursor[d], 1)] = make_int2(s, __float_as_int(__expf(e)));
    }
  }
}

// ---------------- aggregation v3: one 16-lane group per node, half8 gathers ----------------
__global__ __launch_bounds__(256) void k_agg(const _Float16* __restrict__ h,
                                             const int* __restrict__ rowptr,
                                             const int* __restrict__ counts,
                                             const int2* __restrict__ colsw,
                                             const float* __restrict__ bias,
                                             _Float16* __restrict__ eh, int N) {
  int tid = threadIdx.x;
  int v = blockIdx.x * 16 + (tid >> 4);
  if (v >= N) return;
  int lane = tid & 63;
  int gidx = lane & 15;
  int grpb = lane & 48;
  int start = rowptr[v], deg = counts[v];

  float acc[8];
#pragma unroll
  for (int t = 0; t < 8; ++t) acc[t] = 0.f;
  float den = 0.f;

  for (int base = 0; base < deg; base += 16) {
    int cnt = deg - base; if (cnt > 16) cnt = 16;
    int u_l = 0; float w_l = 0.f;
    if (gidx < cnt) {
      int2 p = colsw[start + base + gidx];
      u_l = p.x;
      w_l = __int_as_float(p.y);
    }
    den += group_sum16(w_l);
    for (int j = 0; j < cnt; j += 4) {
      int   u0 = __shfl(u_l, grpb | (j + 0), 64), u1 = __shfl(u_l, grpb | (j + 1), 64);
      int   u2 = __shfl(u_l, grpb | (j + 2), 64), u3 = __shfl(u_l, grpb | (j + 3), 64);
      float w0 = __shfl(w_l, grpb | (j + 0), 64), w1 = __shfl(w_l, grpb | (j + 1), 64);
      float w2 = __shfl(w_l, grpb | (j + 2), 64), w3 = __shfl(w_l, grpb | (j + 3), 64);
      half8 h0 = *(const half8*)(h + (size_t)u0 * HID + gidx * 8);
      half8 h1 = *(const half8*)(h + (size_t)u1 * HID + gidx * 8);
      half8 h2 = *(const half8*)(h + (size_t)u2 * HID + gidx * 8);
      half8 h3 = *(const half8*)(h + (size_t)u3 * HID + gidx * 8);
#pragma unroll
      for (int t = 0; t < 8; ++t) {
        acc[t] = fmaf(w0, (float)h0[t], acc[t]);
        acc[t] = fmaf(w1, (float)h1[t], acc[t]);
        acc[t] = fmaf(w2, (float)h2[t], acc[t]);
        acc[t] = fmaf(w3, (float)h3[t], acc[t]);
      }
    }
  }
  float inv = 1.f / den;
  float4 b0 = *(const float4*)(bias + gidx * 8);
  float4 b1 = *(const float4*)(bias + gidx * 8 + 4);
  float bf[8] = {b0.x, b0.y, b0.z, b0.w, b1.x, b1.y, b1.z, b1.w};
  half8 o;
#pragma unroll
  for (int t = 0; t < 8; ++t) {
    float x = acc[t] * inv + bf[t];
    o[t] = (_Float16)((x > 0.f) ? x : (__expf(x) - 1.f));
  }
  *(half8*)(eh + (size_t)v * HID + gidx * 8) = o;
}

// ---------------- GEMM2 + q: embed = eh @ W_enc, then DEC assignment ----------------
__global__ __launch_bounds__(256) void k_gemm2q(const _Float16* __restrict__ A,
                                                const _Float16* __restrict__ Bt,
                                                const float* __restrict__ cent,
                                                float* __restrict__ C,
                                                _Float16* __restrict__ C16,
                                                float* __restrict__ q, int M) {
  __shared__ _Float16 As[128 * 136];
  __shared__ _Float16 Bs[64 * 136];
  const int tid = threadIdx.x;
  const int lane = tid & 63, wid = tid >> 6;
  const int wrow = (wid >> 1) * 64, wcol = (wid & 1) * 32;
  const int row0 = blockIdx.x * 128;
  const int l31 = lane & 31, lhi = lane >> 5;

#pragma unroll
  for (int c = 0; c < 8; ++c) {
    int idx = tid + c * 256;
    int r = idx >> 4, ko = idx & 15;
    int gr = row0 + r;
    half8 hv = {};
    if (gr < M) hv = *(const half8*)(A + (size_t)gr * HID + ko * 8);
    *(half8*)(&As[r * 136 + ko * 8]) = hv;
  }
#pragma unroll
  for (int c = 0; c < 4; ++c) {
    int idx = tid + c * 256;
    int col = idx >> 4, ko = idx & 15;
    *(half8*)(&Bs[col * 136 + ko * 8]) = *(const half8*)(Bt + (size_t)col * HID + ko * 8);
  }
  __syncthreads();

  f32x16 acc[2] = {};
#pragma unroll
  for (int ks = 0; ks < 8; ++ks) {
    half8 a0 = *(half8*)(&As[(wrow + l31) * 136      + ks * 16 + lhi * 8]);
    half8 a1 = *(half8*)(&As[(wrow + 32 + l31) * 136 + ks * 16 + lhi * 8]);
    half8 b0 = *(half8*)(&Bs[(wcol + l31) * 136      + ks * 16 + lhi * 8]);
    acc[0] = __builtin_amdgcn_mfma_f32_32x32x16_f16(a0, b0, acc[0], 0, 0, 0);
    acc[1] = __builtin_amdgcn_mfma_f32_32x32x16_f16(a1, b0, acc[1], 0, 0, 0);
  }
  __syncthreads();

  float* Es = (float*)As;               // [128][68]
  float* Cs = (float*)Bs;               // [20][64]
#pragma unroll
  for (int t = 0; t < 5; ++t) {
    int i = tid + t * 256;
    if (i < KC * OUTD) Cs[i] = cent[i];
  }
#pragma unroll
  for (int mr = 0; mr < 2; ++mr)
#pragma unroll
    for (int r = 0; r < 16; ++r) {
      int lr = wrow + mr * 32 + (r & 3) + 8 * (r >> 2) + 4 * lhi;
      int row = row0 + lr;
      int col = wcol + l31;
      float x = acc[mr][r];
      Es[lr * 68 + col] = x;
      if (row < M) {
        C[(size_t)row * OUTD + col] = x;
        C16[(size_t)row * OUTD + col] = (_Float16)x;
      }
    }
  __syncthreads();

  if (tid < 128) {
    int row = row0 + tid;
    if (row < M) {
      const float* erow = &Es[tid * 68];
      float accq[KC];
#pragma unroll
      for (int k = 0; k < KC; ++k) accq[k] = 0.f;
#pragma unroll
      for (int d0 = 0; d0 < OUTD; d0 += 4) {
        float4 e4 = *(const float4*)(erow + d0);
#pragma unroll
        for (int k = 0; k < KC; ++k) {
          float4 c4 = *(const float4*)(&Cs[k * OUTD + d0]);
          float dx = e4.x - c4.x, dy = e4.y - c4.y, dz = e4.z - c4.z, dw = e4.w - c4.w;
          accq[k] = fmaf(dx, dx, fmaf(dy, dy, fmaf(dz, dz, fmaf(dw, dw, accq[k]))));
        }
      }
      float qs = 0.f;
#pragma unroll
      for (int k = 0; k < KC; ++k) {
        accq[k] = 1.f / (1.f + accq[k] + 1e-8f);
        qs += accq[k];
      }
      float inv = 1.f / qs;
      float* qrow = q + (size_t)row * KC;
#pragma unroll
      for (int k0 = 0; k0 < KC; k0 += 4) {
        float4 o = make_float4(accq[k0] * inv, accq[k0 + 1] * inv,
                               accq[k0 + 2] * inv, accq[k0 + 3] * inv);
        *(float4*)(qrow + k0) = o;
      }
    }
  }
}

// ---------------- GEMM3: pred = elu(embed @ W_dec) ----------------
__global__ __launch_bounds__(256) void k_gemm3(const _Float16* __restrict__ A,
                                               const _Float16* __restrict__ Bt,
                                               float* __restrict__ C, int M) {
  __shared__ _Float16 As[128 * 72];
  __shared__ _Float16 Bs[128 * 72];
  const int tid = threadIdx.x;
  const int lane = tid & 63, wid = tid >> 6;
  const int wrow = (wid >> 1) * 64, wcol = (wid & 1) * 64;
  const int row0 = blockIdx.x * 128;
  const int cb = blockIdx.y * 128;
  const int l31 = lane & 31, lhi = lane >> 5;

#pragma unroll
  for (int c = 0; c < 4; ++c) {
    int idx = tid + c * 256;
    int r = idx >> 3, ko = idx & 7;
    int gr = row0 + r;
    half8 hv = {};
    if (gr < M) hv = *(const half8*)(A + (size_t)gr * OUTD + ko * 8);
    *(half8*)(&As[r * 72 + ko * 8]) = hv;
  }
#pragma unroll
  for (int c = 0; c < 4; ++c) {
    int idx = tid + c * 256;
    int col = idx >> 3, ko = idx & 7;
    *(half8*)(&Bs[col * 72 + ko * 8]) = *(const half8*)(Bt + (size_t)(cb + col) * OUTD + ko * 8);
  }
  __syncthreads();

  f32x16 acc[2][2] = {};
#pragma unroll
  for (int ks = 0; ks < 4; ++ks) {
    half8 a0 = *(half8*)(&As[(wrow + l31) * 72      + ks * 16 + lhi * 8]);
    half8 a1 = *(half8*)(&As[(wrow + 32 + l31) * 72 + ks * 16 + lhi * 8]);
    half8 b0 = *(half8*)(&Bs[(wcol + l31) * 72      + ks * 16 + lhi * 8]);
    half8 b1 = *(half8*)(&Bs[(wcol + 32 + l31) * 72 + ks * 16 + lhi * 8]);
    acc[0][0] = __builtin_amdgcn_mfma_f32_32x32x16_f16(a0, b0, acc[0][0], 0, 0, 0);
    acc[0][1] = __builtin_amdgcn_mfma_f32_32x32x16_f16(a0, b1, acc[0][1], 0, 0, 0);
    acc[1][0] = __builtin_amdgcn_mfma_f32_32x32x16_f16(a1, b0, acc[1][0], 0, 0, 0);
    acc[1][1] = __builtin_amdgcn_mfma_f32_32x32x16_f16(a1, b1, acc[1][1], 0, 0, 0);
  }
#pragma unroll
  for (int mr = 0; mr < 2; ++mr)
#pragma unroll
    for (int r = 0; r < 16; ++r) {
      int row = row0 + wrow + mr * 32 + (r & 3) + 8 * (r >> 2) + 4 * lhi;
      if (row < M) {
#pragma unroll
        for (int nr = 0; nr < 2; ++nr) {
          float x = acc[mr][nr][r];
          C[(size_t)row * IN + cb + wcol + nr * 32 + l31] =
              (x > 0.f) ? x : (__expf(x) - 1.f);
        }
      }
    }
}

static inline size_t align16(size_t x) { return (x + 15) & ~(size_t)15; }

extern "C" void kernel_launch(void* const* d_in, const int* in_sizes, int n_in,
                              void* d_out, int out_size, void* d_ws, size_t ws_size,
                              hipStream_t stream) {
  const float* x      = (const float*)d_in[0];
  const float* W_gat  = (const float*)d_in[1];
  const float* attn_l = (const float*)d_in[2];
  const float* attn_r = (const float*)d_in[3];
  const float* bias   = (const float*)d_in[4];
  const float* W_enc  = (const float*)d_in[5];
  const float* W_dec  = (const float*)d_in[6];
  const float* cent   = (const float*)d_in[7];
  const int*   src    = (const int*)d_in[8];
  const int*   dst    = (const int*)d_in[9];

  const int N = in_sizes[0] / IN;
  const int E = in_sizes[8];

  float* out   = (float*)d_out;
  float* embed = out;                            // N x 64
  float* pred  = out + (size_t)N * OUTD;         // N x 512
  float* qout  = pred + (size_t)N * IN;          // N x 20

  char* w = (char*)d_ws;
  size_t off = 0;
  _Float16* h16   = (_Float16*)(w + off); off = align16(off + sizeof(_Float16) * (size_t)N * HID);
  _Float16* eh16  = (_Float16*)(w + off); off = align16(off + sizeof(_Float16) * (size_t)N * HID);
  _Float16* emb16 = (_Float16*)(w + off); off = align16(off + sizeof(_Float16) * (size_t)N * OUTD);
  float* el       = (float*)(w + off);    off = align16(off + sizeof(float) * (size_t)N);
  float* er       = (float*)(w + off);    off = align16(off + sizeof(float) * (size_t)N);
  _Float16* Bt_g  = (_Float16*)(w + off); off = align16(off + sizeof(_Float16) * HID * IN);
  _Float16* Bt_e  = (_Float16*)(w + off); off = align16(off + sizeof(_Float16) * OUTD * HID);
  _Float16* Bt_d  = (_Float16*)(w + off); off = align16(off + sizeof(_Float16) * IN * OUTD);
  int* counts     = (int*)(w + off);      off = align16(off + sizeof(int) * (size_t)N);
  int* rowptr     = (int*)(w + off);      off = align16(off + sizeof(int) * (size_t)(N + 1));
  int* cursor     = (int*)(w + off);      off = align16(off + sizeof(int) * (size_t)N);
  int2* colsw     = (int2*)(w + off);     off = align16(off + sizeof(int2) * (size_t)E);
  int* bsum       = (int*)(w + off);      off = align16(off + sizeof(int) * 256);

  const int nblk_scan = (N + 511) / 512;
  const int prep_elems = HID * IN + OUTD * HID + IN * OUTD;
  const int nblk_prep = (prep_elems > N ? prep_elems : N);

  hipLaunchKernelGGL(k_prep, dim3((nblk_prep + 255) / 256), dim3(256), 0, stream,
                     W_gat, W_enc, W_dec, Bt_g, Bt_e, Bt_d, counts, N);
  hipLaunchKernelGGL(k_gemm1e, dim3((N + 127) / 128), dim3(256), 0, stream,
                     x, Bt_g, attn_l, attn_r, h16, el, er, N);
  hipLaunchKernelGGL(k_hist, dim3((E / 4 + 255) / 256), dim3(256), 0, stream, dst, counts, E);
  hipLaunchKernelGGL(k_scan1, dim3(nblk_scan), dim3(256), 0, stream, counts, bsum, N);
  hipLaunchKernelGGL(k_scan3m, dim3(nblk_scan), dim3(256), 0, stream,
                     counts, bsum, rowptr, cursor, N, nblk_scan);
  hipLaunchKernelGGL(k_fill, dim3((E / 4 + 255) / 256), dim3(256), 0, stream,
                     src, dst, el, er, cursor, colsw, E);
  hipLaunchKernelGGL(k_agg, dim3((N + 15) / 16), dim3(256), 0, stream,
                     h16, rowptr, counts, colsw, bias, eh16, N);
  hipLaunchKernelGGL(k_gemm2q, dim3((N + 127) / 128), dim3(256), 0, stream,
                     eh16, Bt_e, cent, embed, emb16, qout, N);
  hipLaunchKernelGGL(k_gemm3, dim3((N + 127) / 128, 4), dim3(256), 0, stream, emb16, Bt_d, pred, N);
}